// Round 1
// baseline (402.595 us; speedup 1.0000x reference)
//
#include <hip/hip_runtime.h>
#include <hip/hip_bf16.h>

#define N 2048
#define D 128
#define H 40

typedef __attribute__((ext_vector_type(8))) short short8;
typedef __attribute__((ext_vector_type(4))) float float4v;
typedef __attribute__((ext_vector_type(4))) unsigned short ushort4v;

static __device__ __forceinline__ unsigned short f32_to_bf16(float f) {
  unsigned int u = __builtin_bit_cast(unsigned int, f);
  unsigned int rounding = 0x7FFFu + ((u >> 16) & 1u);
  return (unsigned short)((u + rounding) >> 16);
}

// Kernel 1: per (head, 64-row tile): Q = X*W[h]/sqrt(D) (bf16 row-major),
// XVT = (X*V[h])^T (bf16, [h][e][n]); h==0 blocks also emit X as bf16.
__global__ __launch_bounds__(256)
void prep_kernel(const float* __restrict__ X, const float* __restrict__ W,
                 const float* __restrict__ V, unsigned short* __restrict__ Xb,
                 unsigned short* __restrict__ Qg, unsigned short* __restrict__ XVT) {
  const int h = blockIdx.y;
  const int r0 = blockIdx.x * 64;
  const int tid = threadIdx.x;
  const int wave = tid >> 6;
  const int lane = tid & 63;
  const int lo = lane & 15;
  const int quad = lane >> 4;

  __shared__ __align__(16) unsigned short Xs[64 * 136];   // [row][d], pad 8
  __shared__ __align__(16) unsigned short Ts[128 * 136];  // [col][d] = W^T / V^T, pad 8

  // Stage X tile (fp32 -> bf16). h==0 blocks also write global bf16 X.
  for (int i = tid; i < 64 * 32; i += 256) {
    int row = i >> 5, c4 = i & 31;
    float4v x = *(const float4v*)(X + (r0 + row) * D + c4 * 4);
    ushort4v b;
    b.x = f32_to_bf16(x.x); b.y = f32_to_bf16(x.y);
    b.z = f32_to_bf16(x.z); b.w = f32_to_bf16(x.w);
    Xs[row * 136 + c4 * 4 + 0] = b.x;
    Xs[row * 136 + c4 * 4 + 1] = b.y;
    Xs[row * 136 + c4 * 4 + 2] = b.z;
    Xs[row * 136 + c4 * 4 + 3] = b.w;
    if (h == 0) *(ushort4v*)(Xb + (r0 + row) * D + c4 * 4) = b;
  }

  const float* mats[2] = {W + (size_t)h * D * D, V + (size_t)h * D * D};
  for (int mat = 0; mat < 2; mat++) {
    __syncthreads();  // protect Ts from previous phase's readers
    const float* Mp = mats[mat];
    // Stage transposed: Ts[col][d] = M[d][col]
    for (int i = tid; i < 128 * 32; i += 256) {
      int d = i >> 5, c4 = i & 31;
      float4v w = *(const float4v*)(Mp + d * D + c4 * 4);
      Ts[(c4 * 4 + 0) * 136 + d] = f32_to_bf16(w.x);
      Ts[(c4 * 4 + 1) * 136 + d] = f32_to_bf16(w.y);
      Ts[(c4 * 4 + 2) * 136 + d] = f32_to_bf16(w.z);
      Ts[(c4 * 4 + 3) * 136 + d] = f32_to_bf16(w.w);
    }
    __syncthreads();

    float4v acc[8];
#pragma unroll
    for (int n = 0; n < 8; n++) acc[n] = (float4v)(0.0f);
#pragma unroll
    for (int ks = 0; ks < 4; ks++) {
      short8 a = *(const short8*)(Xs + (wave * 16 + lo) * 136 + ks * 32 + quad * 8);
#pragma unroll
      for (int n = 0; n < 8; n++) {
        short8 b = *(const short8*)(Ts + (n * 16 + lo) * 136 + ks * 32 + quad * 8);
        acc[n] = __builtin_amdgcn_mfma_f32_16x16x32_bf16(a, b, acc[n], 0, 0, 0);
      }
    }

    if (mat == 0) {
      const float scale = 0.08838834764831845f;  // 1/sqrt(128)
#pragma unroll
      for (int n = 0; n < 8; n++)
#pragma unroll
        for (int reg = 0; reg < 4; reg++) {
          int row = r0 + wave * 16 + quad * 4 + reg;
          int col = n * 16 + lo;
          Qg[((size_t)h * N + row) * D + col] = f32_to_bf16(acc[n][reg] * scale);
        }
    } else {
#pragma unroll
      for (int n = 0; n < 8; n++)
#pragma unroll
        for (int reg = 0; reg < 4; reg++) {
          int row = r0 + wave * 16 + quad * 4 + reg;
          int col = n * 16 + lo;
          XVT[((size_t)h * D + col) * N + row] = f32_to_bf16(acc[n][reg]);
        }
    }
  }
}

// Kernel 2: flash attention per (head, 64 q-rows); online softmax; MFMA bf16.
// Accumulates over heads into out via fp32 atomicAdd.
__global__ __launch_bounds__(256)
void attn_kernel(const unsigned short* __restrict__ Xb,
                 const unsigned short* __restrict__ Qg,
                 const unsigned short* __restrict__ XVT,
                 float* __restrict__ out) {
  const int h = blockIdx.y;
  const int q0 = blockIdx.x * 64;
  const int tid = threadIdx.x;
  const int wave = tid >> 6;
  const int lane = tid & 63;
  const int lo = lane & 15;
  const int quad = lane >> 4;

  __shared__ __align__(16) unsigned short Ks[64 * 136];  // K tile [key][d], pad 8
  __shared__ __align__(16) unsigned short Vs[128 * 72];  // XVT tile [e][key], pad 8
  __shared__ __align__(16) unsigned short Ps[64 * 72];   // P tile [q][key], pad 8

  // Q A-fragments, held in registers for the whole block lifetime.
  short8 qf[4];
#pragma unroll
  for (int ks = 0; ks < 4; ks++)
    qf[ks] = *(const short8*)(Qg + ((size_t)h * N + q0 + wave * 16 + lo) * D + ks * 32 + quad * 8);

  float4v oacc[8];
#pragma unroll
  for (int n = 0; n < 8; n++) oacc[n] = (float4v)(0.0f);
  float m_run[4], l_run[4];
#pragma unroll
  for (int r = 0; r < 4; r++) { m_run[r] = -1e30f; l_run[r] = 0.0f; }

  for (int kt = 0; kt < N / 64; kt++) {
    const int k0 = kt * 64;
    __syncthreads();  // previous iteration's LDS readers done
    // Stage K tile: 64 x 128 bf16
    for (int i = tid; i < 64 * 16; i += 256) {
      int row = i >> 4, c8 = i & 15;
      *(uint4*)(Ks + row * 136 + c8 * 8) =
          *(const uint4*)(Xb + (k0 + row) * D + c8 * 8);
    }
    // Stage XVT tile: 128 x 64 bf16
    for (int i = tid; i < 128 * 8; i += 256) {
      int e = i >> 3, c8 = i & 7;
      *(uint4*)(Vs + e * 72 + c8 * 8) =
          *(const uint4*)(XVT + ((size_t)h * D + e) * N + k0 + c8 * 8);
    }
    __syncthreads();

    // S = Q @ K^T   (per wave: 16 q-rows x 64 keys)
    float4v sacc[4];
#pragma unroll
    for (int n = 0; n < 4; n++) sacc[n] = (float4v)(0.0f);
#pragma unroll
    for (int ks = 0; ks < 4; ks++) {
#pragma unroll
      for (int n = 0; n < 4; n++) {
        short8 b = *(const short8*)(Ks + (n * 16 + lo) * 136 + ks * 32 + quad * 8);
        sacc[n] = __builtin_amdgcn_mfma_f32_16x16x32_bf16(qf[ks], b, sacc[n], 0, 0, 0);
      }
    }

    // Online softmax update; write P (bf16) to LDS in [q][key] layout.
    float alpha[4];
#pragma unroll
    for (int reg = 0; reg < 4; reg++) {
      float rmax = fmaxf(fmaxf(sacc[0][reg], sacc[1][reg]),
                         fmaxf(sacc[2][reg], sacc[3][reg]));
#pragma unroll
      for (int off = 1; off < 16; off <<= 1)
        rmax = fmaxf(rmax, __shfl_xor(rmax, off));
      float mn = fmaxf(m_run[reg], rmax);
      alpha[reg] = __expf(m_run[reg] - mn);
      m_run[reg] = mn;
      float rsum = 0.0f;
#pragma unroll
      for (int n = 0; n < 4; n++) {
        float p = __expf(sacc[n][reg] - mn);
        rsum += p;
        Ps[(wave * 16 + quad * 4 + reg) * 72 + n * 16 + lo] = f32_to_bf16(p);
      }
#pragma unroll
      for (int off = 1; off < 16; off <<= 1)
        rsum += __shfl_xor(rsum, off);
      l_run[reg] = l_run[reg] * alpha[reg] + rsum;
#pragma unroll
      for (int n = 0; n < 8; n++) oacc[n][reg] *= alpha[reg];
    }
    __syncthreads();  // P visible (wave-local, but keep it safe)

    // O += P @ XV   (per wave: 16 q-rows x 128 e, contraction over 64 keys)
#pragma unroll
    for (int ks = 0; ks < 2; ks++) {
      short8 a = *(const short8*)(Ps + (wave * 16 + lo) * 72 + ks * 32 + quad * 8);
#pragma unroll
      for (int et = 0; et < 8; et++) {
        short8 b = *(const short8*)(Vs + (et * 16 + lo) * 72 + ks * 32 + quad * 8);
        oacc[et] = __builtin_amdgcn_mfma_f32_16x16x32_bf16(a, b, oacc[et], 0, 0, 0);
      }
    }
  }

  // Epilogue: out += O / l  (sum over heads via atomics)
#pragma unroll
  for (int et = 0; et < 8; et++)
#pragma unroll
    for (int reg = 0; reg < 4; reg++) {
      int row = q0 + wave * 16 + quad * 4 + reg;
      int col = et * 16 + lo;
      atomicAdd(out + row * D + col, oacc[et][reg] / l_run[reg]);
    }
}

extern "C" void kernel_launch(void* const* d_in, const int* in_sizes, int n_in,
                              void* d_out, int out_size, void* d_ws, size_t ws_size,
                              hipStream_t stream) {
  const float* X = (const float*)d_in[0];
  const float* W = (const float*)d_in[1];
  const float* V = (const float*)d_in[2];
  float* out = (float*)d_out;

  unsigned short* Xb = (unsigned short*)d_ws;                 // N*D bf16
  unsigned short* Qg = Xb + (size_t)N * D;                    // H*N*D bf16
  unsigned short* XVT = Qg + (size_t)H * N * D;               // H*D*N bf16

  hipMemsetAsync(d_out, 0, (size_t)N * D * sizeof(float), stream);

  dim3 grid(N / 64, H);
  prep_kernel<<<grid, 256, 0, stream>>>(X, W, V, Xb, Qg, XVT);
  attn_kernel<<<grid, 256, 0, stream>>>(Xb, Qg, XVT, out);
}